// Round 3
// baseline (3207.146 us; speedup 1.0000x reference)
//
#include <hip/hip_runtime.h>
#include <hip/hip_bf16.h>

#define D_MODEL 256
#define D_STATE 64
#define MCON    64
#define TLEN    1024
#define BATCH   4
#define NEG_INF -1e9f

// ---------------------------------------------------------------------------
// Kernel 1: per-token projections (unchanged from round 2 — passed).
// ---------------------------------------------------------------------------
__global__ __launch_bounds__(256) void proj_kernel(
    const float* __restrict__ x,
    const float* __restrict__ Wq, const float* __restrict__ bq,
    const float* __restrict__ Wk, const float* __restrict__ bk,
    const float* __restrict__ Wv, const float* __restrict__ bv,
    float* __restrict__ q_ws, float* __restrict__ k_ws, float* __restrict__ v_ws)
{
    const int token = blockIdx.x;
    const int tid = threadIdx.x;
    __shared__ float sx[D_MODEL];
    sx[tid] = x[token * D_MODEL + tid];
    __syncthreads();

    float acc = 0.f;
    #pragma unroll 8
    for (int i = 0; i < D_MODEL; ++i)
        acc += sx[i] * Wv[i * D_MODEL + tid];
    acc += bv[tid];
    v_ws[token * D_MODEL + tid] = acc;

    if (tid < 128) {
        const int j = tid & 63;
        const float* W  = (tid < 64) ? Wq : Wk;
        const float* bb = (tid < 64) ? bq : bk;
        float a = 0.f;
        #pragma unroll 8
        for (int i = 0; i < D_MODEL; ++i)
            a += sx[i] * W[i * D_STATE + j];
        a += bb[j];
        float s2 = a * a;
        #pragma unroll
        for (int off = 1; off < 64; off <<= 1) s2 += __shfl_xor(s2, off, 64);
        float nrm = fmaxf(sqrtf(s2), 1e-12f);
        float o = a / nrm;
        if (tid < 64) q_ws[token * D_STATE + j] = o;
        else          k_ws[token * D_STATE + j] = o;
    }
}

// ---------------------------------------------------------------------------
// Kernel 2: single-wave scan. One 64-lane wave per sequence. No cross-wave
// sync: shfl butterflies + wave-synchronous LDS. Reduction trees that feed
// branch decisions replicate round-2 bit-for-bit.
// ---------------------------------------------------------------------------
__global__ __launch_bounds__(64) void scan_kernel(
    const float* __restrict__ q_ws, const float* __restrict__ k_ws,
    const float* __restrict__ v_ws, float* __restrict__ y_ws,
    const float* __restrict__ ls_p)
{
    const int b = blockIdx.x;
    const int l = threadIdx.x;              // lane 0..63
    const float scale = fminf(expf(ls_p[0]), 100.f);

    __shared__ __align__(16) float sV[MCON * D_MODEL];  // 64 KB, row stride 256
    __shared__ __align__(16) float sC[MCON * 68];       // 17 KB, row stride 68 (16B-aligned rows)
    __shared__ __align__(16) float sQ[D_STATE];
    __shared__ __align__(16) float sE[MCON];

    // zero-init state (w~0 * garbage would still poison z)
    const float4 zero4 = make_float4(0.f, 0.f, 0.f, 0.f);
    #pragma unroll
    for (int i = 0; i < 64; ++i) ((float4*)sV)[i * 64 + l] = zero4;
    #pragma unroll
    for (int i = 0; i < 17; ++i) ((float4*)sC)[i * 64 + l] = zero4;
    float cnt_l = 0.f;   // counts[l] lives in lane l
    int n = 0;           // uniform across lanes

    const float* qg = q_ws + b * TLEN * D_STATE;
    const float* kg = k_ws + b * TLEN * D_STATE;
    const float* vg = v_ws + b * TLEN * D_MODEL;
    float*       yg = y_ws + b * TLEN * D_MODEL;

    // prefetch t = 0
    float  qr = qg[l];
    float  kr = kg[l];
    float4 vr = *(const float4*)&vg[4 * l];

    for (int t = 0; t < TLEN; ++t) {
        sQ[l] = qr;                  // stage q_t
        const float  kk = kr;        // lane l holds k_t[l]
        const float4 vt = vr;        // lane l holds v_t[4l..4l+3]

        // prefetch t+1 (slack = one full step)
        const int tn = (t + 1 < TLEN) ? t + 1 : t;
        const float  qn = qg[tn * D_STATE + l];
        const float  kn = kg[tn * D_STATE + l];
        const float4 vn = *(const float4*)&vg[tn * D_MODEL + 4 * l];

        __syncthreads();   // B0 (1 wave => waitcnt): sQ + prev updates visible

        // ---- sims: lane l computes C[l].q with round-2's 4-partial tree ----
        float p[4];
        #pragma unroll
        for (int part = 0; part < 4; ++part) {
            float acc = 0.f;
            #pragma unroll
            for (int j = 0; j < 4; ++j) {
                const float4 c4 = *(const float4*)&sC[l * 68 + part * 16 + 4 * j];
                const float4 q4 = ((const float4*)sQ)[part * 4 + j];
                acc += c4.x * q4.x; acc += c4.y * q4.y;
                acc += c4.z * q4.z; acc += c4.w * q4.w;
            }
            p[part] = acc;
        }
        const float sim = (p[0] + p[1]) + (p[2] + p[3]);

        // ---- softmax + argmax (round-2 butterflies) ----
        const float lg = ((l < n) ? sim : NEG_INF) * scale;
        float mx = lg;
        #pragma unroll
        for (int off = 1; off < 64; off <<= 1)
            mx = fmaxf(mx, __shfl_xor(mx, off, 64));
        const float e = expf(lg - mx);
        sE[l] = e;
        float sm = e;
        #pragma unroll
        for (int off = 1; off < 64; off <<= 1) sm += __shfl_xor(sm, off, 64);
        const float w = e / sm;
        float bw = w; int bi = l;
        #pragma unroll
        for (int off = 1; off < 64; off <<= 1) {
            const float ow = __shfl_xor(bw, off, 64);
            const int   oi = __shfl_xor(bi, off, 64);
            if (ow > bw || (ow == bw && oi < bi)) { bw = ow; bi = oi; }
        }
        const int   sel    = bi;
        const float selSim = __shfl(sim,   sel, 64);
        const float cnt    = __shfl(cnt_l, sel, 64);

        __syncthreads();   // B1: sE visible

        // ---- broadcast all 64 exp values into registers ----
        float4 ea[16];
        #pragma unroll
        for (int j = 0; j < 16; ++j) ea[j] = ((const float4*)sE)[j];

        // ---- residual (reads V pre-update) ----
        const float4 vsel = *(const float4*)&sV[sel * D_MODEL + 4 * l];
        float r = (vsel.x - vt.x) * (vsel.x - vt.x)
                + (vsel.y - vt.y) * (vsel.y - vt.y)
                + (vsel.z - vt.z) * (vsel.z - vt.z)
                + (vsel.w - vt.w) * (vsel.w - vt.w);
        #pragma unroll
        for (int off = 1; off < 64; off <<= 1) r += __shfl_xor(r, off, 64);
        const float residual = sqrtf(r * (1.f / 256.f));

        // ---- z = (sum_m e_m * V[m][4l..]) / sm  (z feeds no branches) ----
        float4 zacc = make_float4(0.f, 0.f, 0.f, 0.f);
        #pragma unroll
        for (int j = 0; j < 16; ++j) {
            const float* vb = &sV[(4 * j) * D_MODEL + 4 * l];
            const float4 v0 = *(const float4*)(vb);
            const float4 v1 = *(const float4*)(vb + D_MODEL);
            const float4 v2 = *(const float4*)(vb + 2 * D_MODEL);
            const float4 v3 = *(const float4*)(vb + 3 * D_MODEL);
            const float4 e4 = ea[j];
            zacc.x += e4.x * v0.x + e4.y * v1.x + e4.z * v2.x + e4.w * v3.x;
            zacc.y += e4.x * v0.y + e4.y * v1.y + e4.z * v2.y + e4.w * v3.y;
            zacc.z += e4.x * v0.z + e4.y * v1.z + e4.z * v2.z + e4.w * v3.z;
            zacc.w += e4.x * v0.w + e4.y * v1.w + e4.z * v2.w + e4.w * v3.w;
        }

        // ---- flags (uniform) ----
        const bool has       = n > 0;
        const bool refine    = has && (n < MCON) &&
                               (selSim < 0.75f || residual > 1.0f);
        const bool do_add    = ((!has) || refine) && (n < MCON);
        const bool do_update = has && !refine;

        float4 zout;
        zout.x = has ? zacc.x / sm : 0.f;
        zout.y = has ? zacc.y / sm : 0.f;
        zout.z = has ? zacc.z / sm : 0.f;
        zout.w = has ? zacc.w / sm : 0.f;
        *(float4*)&yg[t * D_MODEL + 4 * l] = zout;

        // ---- state updates ----
        if (do_update) {
            float4 nv;
            nv.x = (vsel.x * cnt + vt.x) / (cnt + 1.f);
            nv.y = (vsel.y * cnt + vt.y) / (cnt + 1.f);
            nv.z = (vsel.z * cnt + vt.z) / (cnt + 1.f);
            nv.w = (vsel.w * cnt + vt.w) / (cnt + 1.f);
            *(float4*)&sV[sel * D_MODEL + 4 * l] = nv;
        }
        if (do_add) *(float4*)&sV[n * D_MODEL + 4 * l] = vt;

        if (do_update) {
            const float c   = sC[sel * 68 + l];
            const float tmp = 0.9f * c + 0.1f * kk;
            float s2 = tmp * tmp;
            #pragma unroll
            for (int off = 1; off < 64; off <<= 1) s2 += __shfl_xor(s2, off, 64);
            sC[sel * 68 + l] = tmp / fmaxf(sqrtf(s2), 1e-12f);
        }
        if (do_add) sC[n * 68 + l] = kk;

        if (l == sel && do_update) cnt_l = cnt + 1.f;
        if (l == n   && do_add)    cnt_l = 1.f;
        n += do_add ? 1 : 0;

        qr = qn; kr = kn; vr = vn;
    }
}

// ---------------------------------------------------------------------------
// Kernel 3: out = y @ Wo + bo (unchanged from round 2 — passed).
// ---------------------------------------------------------------------------
__global__ __launch_bounds__(256) void out_kernel(
    const float* __restrict__ y_ws,
    const float* __restrict__ Wo, const float* __restrict__ bo,
    float* __restrict__ out)
{
    const int token = blockIdx.x;
    const int tid = threadIdx.x;
    __shared__ float sy[D_MODEL];
    sy[tid] = y_ws[token * D_MODEL + tid];
    __syncthreads();
    float acc = 0.f;
    #pragma unroll 8
    for (int i = 0; i < D_MODEL; ++i)
        acc += sy[i] * Wo[i * D_MODEL + tid];
    acc += bo[tid];
    out[token * D_MODEL + tid] = acc;
}

// ---------------------------------------------------------------------------
extern "C" void kernel_launch(void* const* d_in, const int* in_sizes, int n_in,
                              void* d_out, int out_size, void* d_ws, size_t ws_size,
                              hipStream_t stream)
{
    const float* x  = (const float*)d_in[0];
    const float* Wq = (const float*)d_in[1];
    const float* bq = (const float*)d_in[2];
    const float* Wk = (const float*)d_in[3];
    const float* bk = (const float*)d_in[4];
    const float* Wv = (const float*)d_in[5];
    const float* bv = (const float*)d_in[6];
    const float* Wo = (const float*)d_in[7];
    const float* bo = (const float*)d_in[8];
    const float* ls = (const float*)d_in[9];
    float* out = (float*)d_out;

    const int NTOK = BATCH * TLEN;                 // 4096
    char* ws = (char*)d_ws;
    float* q_ws = (float*)ws;                                       // 1 MB
    float* k_ws = (float*)(ws + (size_t)NTOK * D_STATE * 4);        // 1 MB
    float* v_ws = (float*)(ws + (size_t)NTOK * D_STATE * 8);        // 4 MB
    float* y_ws = (float*)(ws + (size_t)NTOK * D_STATE * 8
                              + (size_t)NTOK * D_MODEL * 4);        // 4 MB

    proj_kernel<<<NTOK, 256, 0, stream>>>(x, Wq, bq, Wk, bk, Wv, bv,
                                          q_ws, k_ws, v_ws);
    scan_kernel<<<BATCH, 64, 0, stream>>>(q_ws, k_ws, v_ws, y_ws, ls);
    out_kernel<<<NTOK, 256, 0, stream>>>(y_ws, Wo, bo, out);
}

// Round 5
// 2464.732 us; speedup vs baseline: 1.3012x; 1.3012x over previous
//
#include <hip/hip_runtime.h>
#include <hip/hip_bf16.h>

#define D_MODEL 256
#define D_STATE 64
#define MCON    64
#define TLEN    1024
#define BATCH   4
#define NEG_INF -1e9f

// ---------------- DPP wave-64 reduction helpers (no DS-pipe traffic) -------
// ctrl/row_mask must be literal constants -> template non-type params.
template <int CTRL, int RM>
__device__ __forceinline__ float dpp_f(float x) {
    int xi = __float_as_int(x);
    int r  = __builtin_amdgcn_update_dpp(xi, xi, CTRL, RM, 0xf, false);
    return __int_as_float(r);
}
template <int CTRL, int RM>
__device__ __forceinline__ int dpp_i(int x) {
    return __builtin_amdgcn_update_dpp(x, x, CTRL, RM, 0xf, false);
}
__device__ __forceinline__ float bcast_lane(float x, int lane) {
    return __int_as_float(__builtin_amdgcn_readlane(__float_as_int(x), lane));
}
// full-wave sum, result broadcast from lane 63 (shr-tree + row bcasts)
__device__ __forceinline__ float wave_sum(float x) {
    x += dpp_f<0x111, 0xf>(x);   // row_shr:1
    x += dpp_f<0x112, 0xf>(x);   // row_shr:2
    x += dpp_f<0x114, 0xf>(x);   // row_shr:4
    x += dpp_f<0x118, 0xf>(x);   // row_shr:8
    x += dpp_f<0x142, 0xa>(x);   // row_bcast15 -> rows 1,3
    x += dpp_f<0x143, 0xc>(x);   // row_bcast31 -> row 3 (and 1, masked)
    return bcast_lane(x, 63);
}
// full-wave max (exact, order-insensitive)
__device__ __forceinline__ float wave_max(float x) {
    x = fmaxf(x, dpp_f<0x111, 0xf>(x));
    x = fmaxf(x, dpp_f<0x112, 0xf>(x));
    x = fmaxf(x, dpp_f<0x114, 0xf>(x));
    x = fmaxf(x, dpp_f<0x118, 0xf>(x));
    x = fmaxf(x, dpp_f<0x142, 0xa>(x));
    x = fmaxf(x, dpp_f<0x143, 0xc>(x));
    return bcast_lane(x, 63);
}
// argmax with lowest-index tiebreak (exact: associative & commutative)
template <int CTRL, int RM>
__device__ __forceinline__ void maxarg_stage(float& v, int& i) {
    float ov = dpp_f<CTRL, RM>(v);
    int   oi = dpp_i<CTRL, RM>(i);
    const bool better = (ov > v) || (ov == v && oi < i);
    v = better ? ov : v;
    i = better ? oi : i;
}
__device__ __forceinline__ int wave_argmax(float v, int lane) {
    int i = lane;
    maxarg_stage<0x111, 0xf>(v, i);
    maxarg_stage<0x112, 0xf>(v, i);
    maxarg_stage<0x114, 0xf>(v, i);
    maxarg_stage<0x118, 0xf>(v, i);
    maxarg_stage<0x142, 0xa>(v, i);
    maxarg_stage<0x143, 0xc>(v, i);
    return __builtin_amdgcn_readlane(i, 63);
}

// ---------------------------------------------------------------------------
// Kernel 1: per-token projections (unchanged — passed R2/R3).
// ---------------------------------------------------------------------------
__global__ __launch_bounds__(256) void proj_kernel(
    const float* __restrict__ x,
    const float* __restrict__ Wq, const float* __restrict__ bq,
    const float* __restrict__ Wk, const float* __restrict__ bk,
    const float* __restrict__ Wv, const float* __restrict__ bv,
    float* __restrict__ q_ws, float* __restrict__ k_ws, float* __restrict__ v_ws)
{
    const int token = blockIdx.x;
    const int tid = threadIdx.x;
    __shared__ float sx[D_MODEL];
    sx[tid] = x[token * D_MODEL + tid];
    __syncthreads();

    float acc = 0.f;
    #pragma unroll 8
    for (int i = 0; i < D_MODEL; ++i)
        acc += sx[i] * Wv[i * D_MODEL + tid];
    acc += bv[tid];
    v_ws[token * D_MODEL + tid] = acc;

    if (tid < 128) {
        const int j = tid & 63;
        const float* W  = (tid < 64) ? Wq : Wk;
        const float* bb = (tid < 64) ? bq : bk;
        float a = 0.f;
        #pragma unroll 8
        for (int i = 0; i < D_MODEL; ++i)
            a += sx[i] * W[i * D_STATE + j];
        a += bb[j];
        float s2 = a * a;
        #pragma unroll
        for (int off = 1; off < 64; off <<= 1) s2 += __shfl_xor(s2, off, 64);
        float nrm = fmaxf(sqrtf(s2), 1e-12f);
        float o = a / nrm;
        if (tid < 64) q_ws[token * D_STATE + j] = o;
        else          k_ws[token * D_STATE + j] = o;
    }
}

// ---------------------------------------------------------------------------
// Kernel 2: single-wave scan, DPP reductions (no ds_bpermute on the chain).
// ---------------------------------------------------------------------------
__global__ __launch_bounds__(64) void scan_kernel(
    const float* __restrict__ q_ws, const float* __restrict__ k_ws,
    const float* __restrict__ v_ws, float* __restrict__ y_ws,
    const float* __restrict__ ls_p)
{
    const int b = blockIdx.x;
    const int l = threadIdx.x;              // lane 0..63
    const float scale = fminf(expf(ls_p[0]), 100.f);

    __shared__ __align__(16) float sV[MCON * D_MODEL];  // 64 KB, row stride 256
    __shared__ __align__(16) float sC[MCON * 68];       // row stride 68 (16B-aligned rows)
    __shared__ __align__(16) float sQ[D_STATE];

    const float4 zero4 = make_float4(0.f, 0.f, 0.f, 0.f);
    #pragma unroll
    for (int i = 0; i < 64; ++i) ((float4*)sV)[i * 64 + l] = zero4;
    #pragma unroll
    for (int i = 0; i < 17; ++i) ((float4*)sC)[i * 64 + l] = zero4;
    float cnt_l = 0.f;   // counts[l] in lane l
    int n = 0;           // uniform
    __syncthreads();

    const float* qg = q_ws + b * TLEN * D_STATE;
    const float* kg = k_ws + b * TLEN * D_STATE;
    const float* vg = v_ws + b * TLEN * D_MODEL;
    float*       yg = y_ws + b * TLEN * D_MODEL;

    float  qr = qg[l];
    float  kr = kg[l];
    float4 vr = *(const float4*)&vg[4 * l];

    for (int t = 0; t < TLEN; ++t) {
        sQ[l] = qr;
        const float  kk = kr;
        const float4 vt = vr;

        const int tn = (t + 1 < TLEN) ? t + 1 : t;
        const float  qn = qg[tn * D_STATE + l];
        const float  kn = kg[tn * D_STATE + l];
        const float4 vn = *(const float4*)&vg[tn * D_MODEL + 4 * l];

        __syncthreads();   // 1 wave: cheap fence (sQ + prev C/V updates)

        // ---- sims: lane l computes C[l].q (same per-lane tree as R3) ----
        float p[4];
        #pragma unroll
        for (int part = 0; part < 4; ++part) {
            float acc = 0.f;
            #pragma unroll
            for (int j = 0; j < 4; ++j) {
                const float4 c4 = *(const float4*)&sC[l * 68 + part * 16 + 4 * j];
                const float4 q4 = ((const float4*)sQ)[part * 4 + j];
                acc += c4.x * q4.x; acc += c4.y * q4.y;
                acc += c4.z * q4.z; acc += c4.w * q4.w;
            }
            p[part] = acc;
        }
        const float sim = (p[0] + p[1]) + (p[2] + p[3]);

        // ---- softmax (DPP) ----
        const float lg = ((l < n) ? sim : NEG_INF) * scale;
        const float mx = wave_max(lg);          // exact max
        const float e  = expf(lg - mx);
        const float sm = wave_sum(e);
        const float w  = e / sm;                // same div op as R2/R3
        const int   sel = wave_argmax(w, l);    // exact tiebreak over w
        const float selSim = bcast_lane(sim,   sel);
        const float cnt    = bcast_lane(cnt_l, sel);
        const int   wbits  = __float_as_int(w);

        // ---- residual (reads V[sel] pre-update) ----
        const float4 vsel = *(const float4*)&sV[sel * D_MODEL + 4 * l];
        float r = (vsel.x - vt.x) * (vsel.x - vt.x)
                + (vsel.y - vt.y) * (vsel.y - vt.y)
                + (vsel.z - vt.z) * (vsel.z - vt.z)
                + (vsel.w - vt.w) * (vsel.w - vt.w);
        const float residual = sqrtf(wave_sum(r) * (1.f / 256.f));

        // ---- z = sum_m w_m * V[m][4l..]  (w_m via readlane, off DS pipe) ----
        float4 zacc = make_float4(0.f, 0.f, 0.f, 0.f);
        #pragma unroll
        for (int j = 0; j < 16; ++j) {
            const float e0 = __int_as_float(__builtin_amdgcn_readlane(wbits, 4 * j + 0));
            const float e1 = __int_as_float(__builtin_amdgcn_readlane(wbits, 4 * j + 1));
            const float e2 = __int_as_float(__builtin_amdgcn_readlane(wbits, 4 * j + 2));
            const float e3 = __int_as_float(__builtin_amdgcn_readlane(wbits, 4 * j + 3));
            const float* vb = &sV[(4 * j) * D_MODEL + 4 * l];
            const float4 v0 = *(const float4*)(vb);
            const float4 v1 = *(const float4*)(vb + D_MODEL);
            const float4 v2 = *(const float4*)(vb + 2 * D_MODEL);
            const float4 v3 = *(const float4*)(vb + 3 * D_MODEL);
            zacc.x += e0 * v0.x + e1 * v1.x + e2 * v2.x + e3 * v3.x;
            zacc.y += e0 * v0.y + e1 * v1.y + e2 * v2.y + e3 * v3.y;
            zacc.z += e0 * v0.z + e1 * v1.z + e2 * v2.z + e3 * v3.z;
            zacc.w += e0 * v0.w + e1 * v1.w + e2 * v2.w + e3 * v3.w;
        }

        // ---- flags (uniform) ----
        const bool has       = n > 0;
        const bool refine    = has && (n < MCON) &&
                               (selSim < 0.75f || residual > 1.0f);
        const bool do_add    = ((!has) || refine) && (n < MCON);
        const bool do_update = has && !refine;

        float4 zout;
        zout.x = has ? zacc.x : 0.f;
        zout.y = has ? zacc.y : 0.f;
        zout.z = has ? zacc.z : 0.f;
        zout.w = has ? zacc.w : 0.f;
        *(float4*)&yg[t * D_MODEL + 4 * l] = zout;

        // ---- state updates (after all V reads of this step) ----
        if (do_update) {
            float4 nv;
            nv.x = (vsel.x * cnt + vt.x) / (cnt + 1.f);
            nv.y = (vsel.y * cnt + vt.y) / (cnt + 1.f);
            nv.z = (vsel.z * cnt + vt.z) / (cnt + 1.f);
            nv.w = (vsel.w * cnt + vt.w) / (cnt + 1.f);
            *(float4*)&sV[sel * D_MODEL + 4 * l] = nv;
        }
        if (do_add) *(float4*)&sV[n * D_MODEL + 4 * l] = vt;

        if (do_update) {
            const float c   = sC[sel * 68 + l];
            const float tmp = 0.9f * c + 0.1f * kk;
            const float s2  = wave_sum(tmp * tmp);
            sC[sel * 68 + l] = tmp / fmaxf(sqrtf(s2), 1e-12f);
        }
        if (do_add) sC[n * 68 + l] = kk;

        if (l == sel && do_update) cnt_l = cnt + 1.f;
        if (l == n   && do_add)    cnt_l = 1.f;
        n += do_add ? 1 : 0;

        qr = qn; kr = kn; vr = vn;
    }
}

// ---------------------------------------------------------------------------
// Kernel 3: out = y @ Wo + bo (unchanged — passed R2/R3).
// ---------------------------------------------------------------------------
__global__ __launch_bounds__(256) void out_kernel(
    const float* __restrict__ y_ws,
    const float* __restrict__ Wo, const float* __restrict__ bo,
    float* __restrict__ out)
{
    const int token = blockIdx.x;
    const int tid = threadIdx.x;
    __shared__ float sy[D_MODEL];
    sy[tid] = y_ws[token * D_MODEL + tid];
    __syncthreads();
    float acc = 0.f;
    #pragma unroll 8
    for (int i = 0; i < D_MODEL; ++i)
        acc += sy[i] * Wo[i * D_MODEL + tid];
    acc += bo[tid];
    out[token * D_MODEL + tid] = acc;
}

// ---------------------------------------------------------------------------
extern "C" void kernel_launch(void* const* d_in, const int* in_sizes, int n_in,
                              void* d_out, int out_size, void* d_ws, size_t ws_size,
                              hipStream_t stream)
{
    const float* x  = (const float*)d_in[0];
    const float* Wq = (const float*)d_in[1];
    const float* bq = (const float*)d_in[2];
    const float* Wk = (const float*)d_in[3];
    const float* bk = (const float*)d_in[4];
    const float* Wv = (const float*)d_in[5];
    const float* bv = (const float*)d_in[6];
    const float* Wo = (const float*)d_in[7];
    const float* bo = (const float*)d_in[8];
    const float* ls = (const float*)d_in[9];
    float* out = (float*)d_out;

    const int NTOK = BATCH * TLEN;                 // 4096
    char* ws = (char*)d_ws;
    float* q_ws = (float*)ws;                                       // 1 MB
    float* k_ws = (float*)(ws + (size_t)NTOK * D_STATE * 4);        // 1 MB
    float* v_ws = (float*)(ws + (size_t)NTOK * D_STATE * 8);        // 4 MB
    float* y_ws = (float*)(ws + (size_t)NTOK * D_STATE * 8
                              + (size_t)NTOK * D_MODEL * 4);        // 4 MB

    proj_kernel<<<NTOK, 256, 0, stream>>>(x, Wq, bq, Wk, bk, Wv, bv,
                                          q_ws, k_ws, v_ws);
    scan_kernel<<<BATCH, 64, 0, stream>>>(q_ws, k_ws, v_ws, y_ws, ls);
    out_kernel<<<NTOK, 256, 0, stream>>>(y_ws, Wo, bo, out);
}

// Round 6
// 2261.394 us; speedup vs baseline: 1.4182x; 1.0899x over previous
//
#include <hip/hip_runtime.h>
#include <hip/hip_bf16.h>

#define D_MODEL 256
#define D_STATE 64
#define MCON    64
#define TLEN    1024
#define BATCH   4
#define NEG_INF -1e9f
#define CSTRIDE 68

// ---------------- DPP wave-64 helpers (ctrl as template constants) ---------
template <int CTRL, int RM>
__device__ __forceinline__ float dpp_f(float x) {
    int xi = __float_as_int(x);
    int r  = __builtin_amdgcn_update_dpp(xi, xi, CTRL, RM, 0xf, false);
    return __int_as_float(r);
}
template <int CTRL, int RM>
__device__ __forceinline__ int dpp_i(int x) {
    return __builtin_amdgcn_update_dpp(x, x, CTRL, RM, 0xf, false);
}
__device__ __forceinline__ float bcast_lane(float x, int lane) {
    return __int_as_float(__builtin_amdgcn_readlane(__float_as_int(x), lane));
}
__device__ __forceinline__ float wave_sum(float x) {
    x += dpp_f<0x111, 0xf>(x);   // row_shr:1
    x += dpp_f<0x112, 0xf>(x);   // row_shr:2
    x += dpp_f<0x114, 0xf>(x);   // row_shr:4
    x += dpp_f<0x118, 0xf>(x);   // row_shr:8
    x += dpp_f<0x142, 0xa>(x);   // row_bcast15
    x += dpp_f<0x143, 0xc>(x);   // row_bcast31
    return bcast_lane(x, 63);
}
__device__ __forceinline__ float wave_max(float x) {
    x = fmaxf(x, dpp_f<0x111, 0xf>(x));
    x = fmaxf(x, dpp_f<0x112, 0xf>(x));
    x = fmaxf(x, dpp_f<0x114, 0xf>(x));
    x = fmaxf(x, dpp_f<0x118, 0xf>(x));
    x = fmaxf(x, dpp_f<0x142, 0xa>(x));
    x = fmaxf(x, dpp_f<0x143, 0xc>(x));
    return bcast_lane(x, 63);
}
template <int CTRL, int RM>
__device__ __forceinline__ void maxarg_stage(float& v, int& i) {
    float ov = dpp_f<CTRL, RM>(v);
    int   oi = dpp_i<CTRL, RM>(i);
    const bool better = (ov > v) || (ov == v && oi < i);
    v = better ? ov : v;
    i = better ? oi : i;
}
__device__ __forceinline__ int wave_argmax(float v, int lane) {
    int i = lane;
    maxarg_stage<0x111, 0xf>(v, i);
    maxarg_stage<0x112, 0xf>(v, i);
    maxarg_stage<0x114, 0xf>(v, i);
    maxarg_stage<0x118, 0xf>(v, i);
    maxarg_stage<0x142, 0xa>(v, i);
    maxarg_stage<0x143, 0xc>(v, i);
    return __builtin_amdgcn_readlane(i, 63);
}
// quad-perm sums: xor1 = [1,0,3,2] = 0xB1, xor2 = [2,3,0,1] = 0x4E
template <int CTRL>
__device__ __forceinline__ float dppq(float x) {
    int xi = __float_as_int(x);
    return __int_as_float(__builtin_amdgcn_update_dpp(xi, xi, CTRL, 0xf, 0xf, false));
}

// ---------------------------------------------------------------------------
// Kernel 1: per-token projections (unchanged — passed R2/R3/R5).
// ---------------------------------------------------------------------------
__global__ __launch_bounds__(256) void proj_kernel(
    const float* __restrict__ x,
    const float* __restrict__ Wq, const float* __restrict__ bq,
    const float* __restrict__ Wk, const float* __restrict__ bk,
    const float* __restrict__ Wv, const float* __restrict__ bv,
    float* __restrict__ q_ws, float* __restrict__ k_ws, float* __restrict__ v_ws)
{
    const int token = blockIdx.x;
    const int tid = threadIdx.x;
    __shared__ float sx[D_MODEL];
    sx[tid] = x[token * D_MODEL + tid];
    __syncthreads();

    float acc = 0.f;
    #pragma unroll 8
    for (int i = 0; i < D_MODEL; ++i)
        acc += sx[i] * Wv[i * D_MODEL + tid];
    acc += bv[tid];
    v_ws[token * D_MODEL + tid] = acc;

    if (tid < 128) {
        const int j = tid & 63;
        const float* W  = (tid < 64) ? Wq : Wk;
        const float* bb = (tid < 64) ? bq : bk;
        float a = 0.f;
        #pragma unroll 8
        for (int i = 0; i < D_MODEL; ++i)
            a += sx[i] * W[i * D_STATE + j];
        a += bb[j];
        float s2 = a * a;
        #pragma unroll
        for (int off = 1; off < 64; off <<= 1) s2 += __shfl_xor(s2, off, 64);
        float nrm = fmaxf(sqrtf(s2), 1e-12f);
        float o = a / nrm;
        if (tid < 64) q_ws[token * D_STATE + j] = o;
        else          k_ws[token * D_STATE + j] = o;
    }
}

// ---------------------------------------------------------------------------
// Kernel 2: 4-wave scan. V in registers (wave w owns rows 16w..16w+15, lane l
// holds cols 4l..4l+3). C in LDS. Softmax redundant on all waves. 3 barriers.
// ---------------------------------------------------------------------------
__global__ __launch_bounds__(256) void scan_kernel(
    const float* __restrict__ q_ws, const float* __restrict__ k_ws,
    const float* __restrict__ v_ws, float* __restrict__ y_ws,
    const float* __restrict__ ls_p)
{
    const int b   = blockIdx.x;
    const int tid = threadIdx.x;
    const int l   = tid & 63;
    const int wv  = tid >> 6;
    const float scale = fminf(expf(ls_p[0]), 100.f);

    __shared__ __align__(16) float sC[MCON * CSTRIDE];  // 17.4 KB
    __shared__ __align__(16) float sQ[D_STATE];
    __shared__ __align__(16) float sSims[MCON];
    __shared__ __align__(16) float sZ[4 * D_MODEL];     // 4 KB partials
    __shared__ float sRes;

    for (int i = tid; i < MCON * CSTRIDE; i += 256) sC[i] = 0.f;

    float4 Vreg[16];
    #pragma unroll
    for (int j = 0; j < 16; ++j) Vreg[j] = make_float4(0.f, 0.f, 0.f, 0.f);
    float cnt_l = 0.f;   // counts[l], replicated per wave
    int n = 0;           // replicated

    const float* qg = q_ws + b * TLEN * D_STATE;
    const float* kg = k_ws + b * TLEN * D_STATE;
    const float* vg = v_ws + b * TLEN * D_MODEL;
    float*       yg = y_ws + b * TLEN * D_MODEL;

    float  qr = (wv == 0) ? qg[l] : 0.f;
    float  kr = (wv == 3) ? kg[l] : 0.f;
    float4 vr = *(const float4*)&vg[4 * l];

    const int row  = (wv << 4) + (l >> 2);   // sims row this lane covers
    const int part = l & 3;                  // 16-elem part within the row

    __syncthreads();   // init visible

    for (int t = 0; t < TLEN; ++t) {
        if (wv == 0) sQ[l] = qr;
        const float  kk = kr;
        const float4 vt = vr;
        __syncthreads();   // B0: sQ + prev-step C writes visible

        // prefetch t+1
        const int tn = (t + 1 < TLEN) ? t + 1 : t;
        const float  qn = (wv == 0) ? qg[tn * D_STATE + l] : 0.f;
        const float  kn = (wv == 3) ? kg[tn * D_STATE + l] : 0.f;
        const float4 vn = *(const float4*)&vg[tn * D_MODEL + 4 * l];

        // ---- sims distributed: lane covers (row, part); tree == R5 ----
        float acc = 0.f;
        #pragma unroll
        for (int j = 0; j < 4; ++j) {
            const float4 c4 = *(const float4*)&sC[row * CSTRIDE + part * 16 + 4 * j];
            const float4 q4 = *(const float4*)&sQ[part * 16 + 4 * j];
            acc += c4.x * q4.x; acc += c4.y * q4.y;
            acc += c4.z * q4.z; acc += c4.w * q4.w;
        }
        acc += dppq<0xB1>(acc);   // p0+p1 (in part-0 lane)
        acc += dppq<0x4E>(acc);   // + (p2+p3)  -> (p0+p1)+(p2+p3)
        if (part == 0) sSims[row] = acc;
        __syncthreads();   // B1: sims visible

        // ---- softmax + argmax, redundant on all waves (bit-identical) ----
        const float simv = sSims[l];
        const float lg = ((l < n) ? simv : NEG_INF) * scale;
        const float mx = wave_max(lg);
        const float e  = expf(lg - mx);
        const float sm = wave_sum(e);
        const float w  = e / sm;
        const int   sel    = wave_argmax(w, l);
        const float selSim = bcast_lane(simv,  sel);
        const float cnt    = bcast_lane(cnt_l, sel);

        // ---- z partial over this wave's 16 rows (pre-update V) ----
        const int wbits = __float_as_int(w);
        const int base  = wv << 4;
        float4 zp = make_float4(0.f, 0.f, 0.f, 0.f);
        #pragma unroll
        for (int j = 0; j < 16; ++j) {
            const float wj = __int_as_float(__builtin_amdgcn_readlane(wbits, base + j));
            zp.x += wj * Vreg[j].x; zp.y += wj * Vreg[j].y;
            zp.z += wj * Vreg[j].z; zp.w += wj * Vreg[j].w;
        }
        *(float4*)&sZ[wv * D_MODEL + 4 * l] = zp;

        // ---- owner wave: select V[sel], residual (pre-update) ----
        const int ws_w = sel >> 4, sidx = sel & 15;
        float4 vs = make_float4(0.f, 0.f, 0.f, 0.f);
        if (wv == ws_w) {
            #pragma unroll
            for (int j = 0; j < 16; ++j) {
                const bool c = (j == sidx);
                vs.x = c ? Vreg[j].x : vs.x;
                vs.y = c ? Vreg[j].y : vs.y;
                vs.z = c ? Vreg[j].z : vs.z;
                vs.w = c ? Vreg[j].w : vs.w;
            }
            float r2 = (vs.x - vt.x) * (vs.x - vt.x)
                     + (vs.y - vt.y) * (vs.y - vt.y)
                     + (vs.z - vt.z) * (vs.z - vt.z)
                     + (vs.w - vt.w) * (vs.w - vt.w);
            r2 = wave_sum(r2);
            if (l == 0) sRes = r2;
        }
        __syncthreads();   // B2: z partials + residual visible

        const float residual = sqrtf(sRes * (1.f / 256.f));
        const bool has       = n > 0;
        const bool refine    = has && (n < MCON) &&
                               (selSim < 0.75f || residual > 1.0f);
        const bool do_add    = ((!has) || refine) && (n < MCON);
        const bool do_update = has && !refine;

        // ---- wave 1: combine z partials, store y ----
        if (wv == 1) {
            const float4 z0 = *(const float4*)&sZ[0 * D_MODEL + 4 * l];
            const float4 z1 = *(const float4*)&sZ[1 * D_MODEL + 4 * l];
            const float4 z2 = *(const float4*)&sZ[2 * D_MODEL + 4 * l];
            const float4 z3 = *(const float4*)&sZ[3 * D_MODEL + 4 * l];
            float4 zout;
            zout.x = has ? ((z0.x + z1.x) + (z2.x + z3.x)) : 0.f;
            zout.y = has ? ((z0.y + z1.y) + (z2.y + z3.y)) : 0.f;
            zout.z = has ? ((z0.z + z1.z) + (z2.z + z3.z)) : 0.f;
            zout.w = has ? ((z0.w + z1.w) + (z2.w + z3.w)) : 0.f;
            *(float4*)&yg[t * D_MODEL + 4 * l] = zout;
        }

        // ---- V updates (register scatter on owner waves) ----
        if (do_update && wv == ws_w) {
            float4 nv;
            nv.x = (vs.x * cnt + vt.x) / (cnt + 1.f);
            nv.y = (vs.y * cnt + vt.y) / (cnt + 1.f);
            nv.z = (vs.z * cnt + vt.z) / (cnt + 1.f);
            nv.w = (vs.w * cnt + vt.w) / (cnt + 1.f);
            #pragma unroll
            for (int j = 0; j < 16; ++j) {
                const bool c = (j == sidx);
                Vreg[j].x = c ? nv.x : Vreg[j].x;
                Vreg[j].y = c ? nv.y : Vreg[j].y;
                Vreg[j].z = c ? nv.z : Vreg[j].z;
                Vreg[j].w = c ? nv.w : Vreg[j].w;
            }
        }
        if (do_add && wv == (n >> 4)) {
            const int aidx = n & 15;
            #pragma unroll
            for (int j = 0; j < 16; ++j) {
                const bool c = (j == aidx);
                Vreg[j].x = c ? vt.x : Vreg[j].x;
                Vreg[j].y = c ? vt.y : Vreg[j].y;
                Vreg[j].z = c ? vt.z : Vreg[j].z;
                Vreg[j].w = c ? vt.w : Vreg[j].w;
            }
        }

        // ---- C update on wave 3 (tree == R5) ----
        if (wv == 3) {
            if (do_update) {
                const float c   = sC[sel * CSTRIDE + l];
                const float tmp = 0.9f * c + 0.1f * kk;
                const float s2  = wave_sum(tmp * tmp);
                sC[sel * CSTRIDE + l] = tmp / fmaxf(sqrtf(s2), 1e-12f);
            }
            if (do_add) sC[n * CSTRIDE + l] = kk;
        }

        // ---- counts / n (replicated, identical on all waves) ----
        if (l == sel && do_update) cnt_l = cnt + 1.f;
        if (l == n   && do_add)    cnt_l = 1.f;
        n += do_add ? 1 : 0;

        qr = qn; kr = kn; vr = vn;
    }
}

// ---------------------------------------------------------------------------
// Kernel 3: out = y @ Wo + bo (unchanged — passed R2/R3/R5).
// ---------------------------------------------------------------------------
__global__ __launch_bounds__(256) void out_kernel(
    const float* __restrict__ y_ws,
    const float* __restrict__ Wo, const float* __restrict__ bo,
    float* __restrict__ out)
{
    const int token = blockIdx.x;
    const int tid = threadIdx.x;
    __shared__ float sy[D_MODEL];
    sy[tid] = y_ws[token * D_MODEL + tid];
    __syncthreads();
    float acc = 0.f;
    #pragma unroll 8
    for (int i = 0; i < D_MODEL; ++i)
        acc += sy[i] * Wo[i * D_MODEL + tid];
    acc += bo[tid];
    out[token * D_MODEL + tid] = acc;
}

// ---------------------------------------------------------------------------
extern "C" void kernel_launch(void* const* d_in, const int* in_sizes, int n_in,
                              void* d_out, int out_size, void* d_ws, size_t ws_size,
                              hipStream_t stream)
{
    const float* x  = (const float*)d_in[0];
    const float* Wq = (const float*)d_in[1];
    const float* bq = (const float*)d_in[2];
    const float* Wk = (const float*)d_in[3];
    const float* bk = (const float*)d_in[4];
    const float* Wv = (const float*)d_in[5];
    const float* bv = (const float*)d_in[6];
    const float* Wo = (const float*)d_in[7];
    const float* bo = (const float*)d_in[8];
    const float* ls = (const float*)d_in[9];
    float* out = (float*)d_out;

    const int NTOK = BATCH * TLEN;                 // 4096
    char* ws = (char*)d_ws;
    float* q_ws = (float*)ws;                                       // 1 MB
    float* k_ws = (float*)(ws + (size_t)NTOK * D_STATE * 4);        // 1 MB
    float* v_ws = (float*)(ws + (size_t)NTOK * D_STATE * 8);        // 4 MB
    float* y_ws = (float*)(ws + (size_t)NTOK * D_STATE * 8
                              + (size_t)NTOK * D_MODEL * 4);        // 4 MB

    proj_kernel<<<NTOK, 256, 0, stream>>>(x, Wq, bq, Wk, bk, Wv, bv,
                                          q_ws, k_ws, v_ws);
    scan_kernel<<<BATCH, 256, 0, stream>>>(q_ws, k_ws, v_ws, y_ws, ls);
    out_kernel<<<NTOK, 256, 0, stream>>>(y_ws, Wo, bo, out);
}